// Round 5
// baseline (1353.720 us; speedup 1.0000x reference)
//
#include <hip/hip_runtime.h>

typedef __attribute__((ext_vector_type(8))) short short8;
typedef __attribute__((ext_vector_type(4))) float f32x4;

constexpr int B_ = 4, S_ = 2048, E_ = 1024, H_ = 8, D_ = 256;
constexpr int HD_ = H_ * D_;   // 2048
constexpr int BS_ = B_ * S_;   // 8192
constexpr int BH_ = B_ * H_;   // 32
constexpr float INV_SQRT_E = 0.03125f;  // 1/sqrt(1024)

__device__ __forceinline__ unsigned short f2bf(float f) {
    union { float f; unsigned u; } x; x.f = f;
    unsigned r = (x.u + 0x7fffu + ((x.u >> 16) & 1u)) >> 16;
    return (unsigned short)r;
}

__device__ __forceinline__ void gl_lds16(const void* g, void* lds) {
    __builtin_amdgcn_global_load_lds((const __attribute__((address_space(1))) void*)g,
                                     (__attribute__((address_space(3))) void*)lds, 16, 0, 0);
}

// ---------------- cast A fp32 -> bf16 (vectorized) ----------------
__global__ __launch_bounds__(256) void cast_k(const float* __restrict__ src,
                                              unsigned short* __restrict__ dst, int n4) {
    int i = blockIdx.x * 256 + threadIdx.x;
    if (i >= n4) return;
    float4 v = reinterpret_cast<const float4*>(src)[i];
    ushort4 o;
    o.x = f2bf(v.x); o.y = f2bf(v.y); o.z = f2bf(v.z); o.w = f2bf(v.w);
    reinterpret_cast<ushort4*>(dst)[i] = o;
}

// ------------- batched transpose+cast: (bt,R,C) f32 -> (bt,C,R) bf16 -------------
__global__ __launch_bounds__(256) void tcast_k(const float* __restrict__ src,
                                               unsigned short* __restrict__ dst, int R, int C) {
    __shared__ float tile[32][33];
    int b = blockIdx.z;
    const float* s = src + (size_t)b * R * C;
    unsigned short* d = dst + (size_t)b * R * C;
    int c0 = blockIdx.x * 32, r0 = blockIdx.y * 32;
    int tx = threadIdx.x, ty = threadIdx.y;
#pragma unroll
    for (int i = 0; i < 4; ++i)
        tile[ty + i * 8][tx] = s[(size_t)(r0 + ty + i * 8) * C + c0 + tx];
    __syncthreads();
#pragma unroll
    for (int i = 0; i < 4; ++i)
        d[(size_t)(c0 + ty + i * 8) * R + r0 + tx] = f2bf(tile[tx][ty + i * 8]);
}

// ------------- bf16 transpose: (BH,S,D) -> (BH,D,S) -------------
__global__ __launch_bounds__(256) void tbf_k(const unsigned short* __restrict__ src,
                                             unsigned short* __restrict__ dst) {
    __shared__ unsigned short tile[32][33];
    int bh = blockIdx.z;
    int d0 = blockIdx.x * 32, s0 = blockIdx.y * 32;
    int tx = threadIdx.x, ty = threadIdx.y;
#pragma unroll
    for (int i = 0; i < 4; ++i)
        tile[ty + i * 8][tx] = src[((size_t)bh * S_ + s0 + ty + i * 8) * D_ + d0 + tx];
    __syncthreads();
#pragma unroll
    for (int i = 0; i < 4; ++i)
        dst[((size_t)bh * D_ + d0 + ty + i * 8) * S_ + s0 + tx] = tile[tx][ty + i * 8];
}

// ------------- QKV GEMM: A(BS,E) x Wt(n)[k] -> relu(+bias) -> (B,H,S,D) bf16 -------------
__global__ __launch_bounds__(256) void gemm_qkv_k(const unsigned short* __restrict__ A,
                                                  const unsigned short* __restrict__ Bt,
                                                  const float* __restrict__ bias,
                                                  unsigned short* __restrict__ out) {
    __shared__ __align__(16) unsigned short As[128 * 32];
    __shared__ __align__(16) unsigned short Bs[128 * 32];
    const int tid = threadIdx.x;
    const int wave = tid >> 6, lane = tid & 63;
    const int quad = lane >> 4, l15 = lane & 15;
    const int wm = wave >> 1, wn = wave & 1;
    const int m0 = blockIdx.y * 128, n0 = blockIdx.x * 128;
    const int c1 = tid, c2 = tid + 256;
    const int r1 = c1 >> 2, kc1 = (c1 & 3) * 8;
    const int r2 = c2 >> 2, kc2 = (c2 & 3) * 8;
    char* aB1 = (char*)As + wave * 1024; char* aB2 = aB1 + 4096;
    char* bB1 = (char*)Bs + wave * 1024; char* bB2 = bB1 + 4096;
    const unsigned short* a1 = A + (size_t)(m0 + r1) * E_ + kc1;
    const unsigned short* a2 = A + (size_t)(m0 + r2) * E_ + kc2;
    const unsigned short* b1 = Bt + (size_t)(n0 + r1) * E_ + kc1;
    const unsigned short* b2 = Bt + (size_t)(n0 + r2) * E_ + kc2;
    f32x4 acc[4][4] = {};
    for (int k0 = 0; k0 < E_; k0 += 32) {
        __syncthreads();
        gl_lds16(a1 + k0, aB1);
        gl_lds16(a2 + k0, aB2);
        gl_lds16(b1 + k0, bB1);
        gl_lds16(b2 + k0, bB2);
        __syncthreads();
        short8 af[4], bf[4];
        const short* Ass = (const short*)As;
        const short* Bss = (const short*)Bs;
#pragma unroll
        for (int f = 0; f < 4; ++f) {
            af[f] = *(const short8*)&Ass[(wm * 64 + f * 16 + l15) * 32 + quad * 8];
            bf[f] = *(const short8*)&Bss[(wn * 64 + f * 16 + l15) * 32 + quad * 8];
        }
#pragma unroll
        for (int fm = 0; fm < 4; ++fm)
#pragma unroll
            for (int fn = 0; fn < 4; ++fn)
                acc[fm][fn] = __builtin_amdgcn_mfma_f32_16x16x32_bf16(af[fm], bf[fn], acc[fm][fn], 0, 0, 0);
    }
#pragma unroll
    for (int fm = 0; fm < 4; ++fm) {
        int mbase = m0 + wm * 64 + fm * 16 + quad * 4;
#pragma unroll
        for (int fn = 0; fn < 4; ++fn) {
            int n = n0 + wn * 64 + fn * 16 + l15;
            int h = n >> 8, d = n & 255;
            float bv = bias[n];
#pragma unroll
            for (int r = 0; r < 4; ++r) {
                int m = mbase + r;
                int b = m >> 11, s = m & 2047;
                float v = fmaxf(acc[fm][fn][r] + bv, 0.0f);
                out[((size_t)(b * H_ + h) * S_ + s) * D_ + d] = f2bf(v);
            }
        }
    }
}

// ------------- output GEMM: Zall(BS,HD) x Wzt(n)[k] + bZ -> fp32 (BS,E) -------------
__global__ __launch_bounds__(256) void gemm_out_k(const unsigned short* __restrict__ A,
                                                  const unsigned short* __restrict__ Bt,
                                                  const float* __restrict__ bias,
                                                  float* __restrict__ out) {
    __shared__ __align__(16) unsigned short As[128 * 32];
    __shared__ __align__(16) unsigned short Bs[128 * 32];
    const int tid = threadIdx.x;
    const int wave = tid >> 6, lane = tid & 63;
    const int quad = lane >> 4, l15 = lane & 15;
    const int wm = wave >> 1, wn = wave & 1;
    const int m0 = blockIdx.y * 128, n0 = blockIdx.x * 128;
    const int c1 = tid, c2 = tid + 256;
    const int r1 = c1 >> 2, kc1 = (c1 & 3) * 8;
    const int r2 = c2 >> 2, kc2 = (c2 & 3) * 8;
    char* aB1 = (char*)As + wave * 1024; char* aB2 = aB1 + 4096;
    char* bB1 = (char*)Bs + wave * 1024; char* bB2 = bB1 + 4096;
    const unsigned short* a1 = A + (size_t)(m0 + r1) * HD_ + kc1;
    const unsigned short* a2 = A + (size_t)(m0 + r2) * HD_ + kc2;
    const unsigned short* b1 = Bt + (size_t)(n0 + r1) * HD_ + kc1;
    const unsigned short* b2 = Bt + (size_t)(n0 + r2) * HD_ + kc2;
    f32x4 acc[4][4] = {};
    for (int k0 = 0; k0 < HD_; k0 += 32) {
        __syncthreads();
        gl_lds16(a1 + k0, aB1);
        gl_lds16(a2 + k0, aB2);
        gl_lds16(b1 + k0, bB1);
        gl_lds16(b2 + k0, bB2);
        __syncthreads();
        short8 af[4], bf[4];
        const short* Ass = (const short*)As;
        const short* Bss = (const short*)Bs;
#pragma unroll
        for (int f = 0; f < 4; ++f) {
            af[f] = *(const short8*)&Ass[(wm * 64 + f * 16 + l15) * 32 + quad * 8];
            bf[f] = *(const short8*)&Bss[(wn * 64 + f * 16 + l15) * 32 + quad * 8];
        }
#pragma unroll
        for (int fm = 0; fm < 4; ++fm)
#pragma unroll
            for (int fn = 0; fn < 4; ++fn)
                acc[fm][fn] = __builtin_amdgcn_mfma_f32_16x16x32_bf16(af[fm], bf[fn], acc[fm][fn], 0, 0, 0);
    }
#pragma unroll
    for (int fm = 0; fm < 4; ++fm) {
        int mbase = m0 + wm * 64 + fm * 16 + quad * 4;
#pragma unroll
        for (int fn = 0; fn < 4; ++fn) {
            int n = n0 + wn * 64 + fn * 16 + l15;
            float bv = bias[n];
#pragma unroll
            for (int r = 0; r < 4; ++r)
                out[(size_t)(mbase + r) * E_ + n] = acc[fm][fn][r] + bv;
        }
    }
}

// ======== colsum_k: invL[t] = 1 / sum_s exp(sc[s][t]) (no max: scores bounded).
// Block owns 64 t-rows. K-tile staged in LDS ONCE; Q B-frags direct from global;
// ZERO barriers in the s-loop. ========
__global__ __launch_bounds__(256) void colsum_k(const unsigned short* __restrict__ Q,
                                                const unsigned short* __restrict__ K,
                                                float* __restrict__ invLcol) {
    __shared__ __align__(16) unsigned short Ks[8 * 64 * 32];  // [kc][row][32] = 32 KB
    __shared__ float part[4][64];
    const int tid = threadIdx.x;
    const int wave = tid >> 6, lane = tid & 63;
    const int quad = lane >> 4, l15 = lane & 15;
    const int bh = blockIdx.y;
    const int t0 = blockIdx.x * 64;
    const unsigned short* Qh = Q + (size_t)bh * S_ * D_;
    const unsigned short* Kh = K + (size_t)bh * S_ * D_;
    const int sr = tid >> 2, scol = (tid & 3) * 8;
#pragma unroll
    for (int kc = 0; kc < 8; ++kc)
        gl_lds16(Kh + (size_t)(t0 + sr) * D_ + kc * 32 + scol,
                 (char*)Ks + kc * 4096 + wave * 1024);
    __syncthreads();
    float rl[4][4] = {};
    for (int s0 = 0; s0 < S_; s0 += 128) {
        f32x4 acc[4][2] = {};
#pragma unroll
        for (int kc = 0; kc < 8; ++kc) {
            short8 af[4];
#pragma unroll
            for (int fm = 0; fm < 4; ++fm)
                af[fm] = *(const short8*)&Ks[kc * 2048 + (fm * 16 + l15) * 32 + quad * 8];
            short8 qb0 = *(const short8*)&Qh[(size_t)(s0 + wave * 32 + l15) * D_ + kc * 32 + quad * 8];
            short8 qb1 = *(const short8*)&Qh[(size_t)(s0 + wave * 32 + 16 + l15) * D_ + kc * 32 + quad * 8];
#pragma unroll
            for (int fm = 0; fm < 4; ++fm) {
                acc[fm][0] = __builtin_amdgcn_mfma_f32_16x16x32_bf16(af[fm], qb0, acc[fm][0], 0, 0, 0);
                acc[fm][1] = __builtin_amdgcn_mfma_f32_16x16x32_bf16(af[fm], qb1, acc[fm][1], 0, 0, 0);
            }
        }
#pragma unroll
        for (int fm = 0; fm < 4; ++fm)
#pragma unroll
            for (int r = 0; r < 4; ++r)
                rl[fm][r] += __expf(acc[fm][0][r] * INV_SQRT_E) +
                             __expf(acc[fm][1][r] * INV_SQRT_E);
    }
#pragma unroll
    for (int fm = 0; fm < 4; ++fm)
#pragma unroll
        for (int r = 0; r < 4; ++r) {
            float v = rl[fm][r];
            v += __shfl_xor(v, 1); v += __shfl_xor(v, 2);
            v += __shfl_xor(v, 4); v += __shfl_xor(v, 8);
            if (l15 == 0) part[wave][fm * 16 + quad * 4 + r] = v;
        }
    __syncthreads();
    if (tid < 64) {
        float s = part[0][tid] + part[1][tid] + part[2][tid] + part[3][tid];
        invLcol[(size_t)bh * S_ + t0 + tid] = 1.0f / s;
    }
}

// ======== flash5_k: flash4 structure, Qs LDS staging REMOVED (Q A-frags from
// global — tile-invariant addresses, L1/L2-hot). LDS = Ps (20 KB) + rsum only;
// __launch_bounds__(256,3) caps VGPR for 3 blocks/CU. 2 barriers per 128-t tile. ========
__global__ __launch_bounds__(256, 3) void flash5_k(const unsigned short* __restrict__ Q,
                                                   const unsigned short* __restrict__ K,
                                                   const unsigned short* __restrict__ Vt,
                                                   const float* __restrict__ invLcol,
                                                   unsigned short* __restrict__ Zall) {
    __shared__ __align__(16) unsigned short Ps[4 * 64 * 40];   // [kk][row][40] = 20 KB
    __shared__ float rsum[64];
    const int tid = threadIdx.x;
    const int wave = tid >> 6, lane = tid & 63;
    const int quad = lane >> 4, l15 = lane & 15;
    const int bh = blockIdx.y;
    const int bb = bh >> 3, hh = bh & 7;
    const int s0 = blockIdx.x * 64;
    const unsigned short* Qh = Q + (size_t)bh * S_ * D_;
    const unsigned short* Kh = K + (size_t)bh * S_ * D_;
    const unsigned short* Vh = Vt + (size_t)bh * D_ * S_;
    const float* Lc = invLcol + (size_t)bh * S_;
    if (tid < 64) rsum[tid] = 0.f;
    f32x4 zacc[4][4] = {};
    float rsacc[4][4] = {};
    __syncthreads();
    for (int t0 = 0; t0 < S_; t0 += 128) {
        f32x4 acc[4][2] = {};
        float Li0 = Lc[t0 + wave * 32 + l15];
        float Li1 = Lc[t0 + wave * 32 + 16 + l15];
#pragma unroll
        for (int kc = 0; kc < 8; ++kc) {
            short8 af[4];
#pragma unroll
            for (int fm = 0; fm < 4; ++fm)
                af[fm] = *(const short8*)&Qh[(size_t)(s0 + fm * 16 + l15) * D_ + kc * 32 + quad * 8];
            short8 kb0 = *(const short8*)&Kh[(size_t)(t0 + wave * 32 + l15) * D_ + kc * 32 + quad * 8];
            short8 kb1 = *(const short8*)&Kh[(size_t)(t0 + wave * 32 + 16 + l15) * D_ + kc * 32 + quad * 8];
#pragma unroll
            for (int fm = 0; fm < 4; ++fm) {
                acc[fm][0] = __builtin_amdgcn_mfma_f32_16x16x32_bf16(af[fm], kb0, acc[fm][0], 0, 0, 0);
                acc[fm][1] = __builtin_amdgcn_mfma_f32_16x16x32_bf16(af[fm], kb1, acc[fm][1], 0, 0, 0);
            }
        }
        // exp(exp(sc)*invL) -> Ps (shared, [kk=wave][row][40])
#pragma unroll
        for (int fm = 0; fm < 4; ++fm)
#pragma unroll
            for (int r = 0; r < 4; ++r) {
                float e0 = __expf(__expf(acc[fm][0][r] * INV_SQRT_E) * Li0);
                float e1 = __expf(__expf(acc[fm][1][r] * INV_SQRT_E) * Li1);
                rsacc[fm][r] += e0 + e1;
                int row = fm * 16 + quad * 4 + r;
                Ps[wave * 2560 + row * 40 + l15] = f2bf(e0);
                Ps[wave * 2560 + row * 40 + 16 + l15] = f2bf(e1);
            }
        __syncthreads();
        // PV: waves split d (64 cols each); A-frags from Ps, B-frags (Vt) from global
#pragma unroll
        for (int kk = 0; kk < 4; ++kk) {
            short8 pa[4], vb[4];
#pragma unroll
            for (int fm = 0; fm < 4; ++fm)
                pa[fm] = *(const short8*)&Ps[kk * 2560 + (fm * 16 + l15) * 40 + quad * 8];
#pragma unroll
            for (int fn = 0; fn < 4; ++fn)
                vb[fn] = *(const short8*)&Vh[(size_t)(wave * 64 + fn * 16 + l15) * S_ + t0 + kk * 32 + quad * 8];
#pragma unroll
            for (int fm = 0; fm < 4; ++fm)
#pragma unroll
                for (int fn = 0; fn < 4; ++fn)
                    zacc[fm][fn] = __builtin_amdgcn_mfma_f32_16x16x32_bf16(pa[fm], vb[fn], zacc[fm][fn], 0, 0, 0);
        }
        __syncthreads();
    }
    // rowsum: each wave holds partials (its t-cols) for ALL 64 rows
#pragma unroll
    for (int fm = 0; fm < 4; ++fm)
#pragma unroll
        for (int r = 0; r < 4; ++r) {
            float v = rsacc[fm][r];
            v += __shfl_xor(v, 1); v += __shfl_xor(v, 2);
            v += __shfl_xor(v, 4); v += __shfl_xor(v, 8);
            if (l15 == 0) atomicAdd(&rsum[fm * 16 + quad * 4 + r], v);
        }
    __syncthreads();
#pragma unroll
    for (int fm = 0; fm < 4; ++fm)
#pragma unroll
        for (int r = 0; r < 4; ++r) {
            int row = fm * 16 + quad * 4 + r;
            float inv = 1.0f / rsum[row];
#pragma unroll
            for (int fn = 0; fn < 4; ++fn)
                Zall[(size_t)(bb * S_ + s0 + row) * HD_ + hh * D_ + wave * 64 + fn * 16 + l15] =
                    f2bf(zacc[fm][fn][r] * inv);
        }
}

extern "C" void kernel_launch(void* const* d_in, const int* in_sizes, int n_in,
                              void* d_out, int out_size, void* d_ws, size_t ws_size,
                              hipStream_t stream) {
    const float* Ain = (const float*)d_in[0];
    const float* WQ = (const float*)d_in[1];
    const float* bQ = (const float*)d_in[2];
    const float* WK = (const float*)d_in[3];
    const float* bK = (const float*)d_in[4];
    const float* WV = (const float*)d_in[5];
    const float* bV = (const float*)d_in[6];
    const float* WZ = (const float*)d_in[7];
    const float* bZ = (const float*)d_in[8];
    float* out = (float*)d_out;

    char* ws = (char*)d_ws;
    size_t off = 0;
    auto alloc = [&](size_t bytes) {
        char* p = ws + off;
        off += (bytes + 255) & ~(size_t)255;
        return p;
    };
    unsigned short* Abf = (unsigned short*)alloc((size_t)BS_ * E_ * 2);
    unsigned short* Wqt = (unsigned short*)alloc((size_t)H_ * D_ * E_ * 2);
    unsigned short* Wkt = (unsigned short*)alloc((size_t)H_ * D_ * E_ * 2);
    unsigned short* Wvt = (unsigned short*)alloc((size_t)H_ * D_ * E_ * 2);
    unsigned short* Wzt = (unsigned short*)alloc((size_t)E_ * HD_ * 2);
    unsigned short* Qb = (unsigned short*)alloc((size_t)BH_ * S_ * D_ * 2);
    unsigned short* Kb = (unsigned short*)alloc((size_t)BH_ * S_ * D_ * 2);
    unsigned short* Vb = (unsigned short*)alloc((size_t)BH_ * S_ * D_ * 2);
    unsigned short* Vtb = (unsigned short*)alloc((size_t)BH_ * S_ * D_ * 2);
    unsigned short* Zb = (unsigned short*)alloc((size_t)BS_ * HD_ * 2);
    float* Lc = (float*)alloc((size_t)BH_ * S_ * 4);

    dim3 tb(32, 8);
    cast_k<<<(BS_ * E_ / 4 + 255) / 256, 256, 0, stream>>>(Ain, Abf, BS_ * E_ / 4);
    tcast_k<<<dim3(D_ / 32, E_ / 32, H_), tb, 0, stream>>>(WQ, Wqt, E_, D_);
    tcast_k<<<dim3(D_ / 32, E_ / 32, H_), tb, 0, stream>>>(WK, Wkt, E_, D_);
    tcast_k<<<dim3(D_ / 32, E_ / 32, H_), tb, 0, stream>>>(WV, Wvt, E_, D_);
    tcast_k<<<dim3(E_ / 32, HD_ / 32, 1), tb, 0, stream>>>(WZ, Wzt, HD_, E_);

    gemm_qkv_k<<<dim3(HD_ / 128, BS_ / 128), 256, 0, stream>>>(Abf, Wqt, bQ, Qb);
    gemm_qkv_k<<<dim3(HD_ / 128, BS_ / 128), 256, 0, stream>>>(Abf, Wkt, bK, Kb);
    gemm_qkv_k<<<dim3(HD_ / 128, BS_ / 128), 256, 0, stream>>>(Abf, Wvt, bV, Vb);

    tbf_k<<<dim3(D_ / 32, S_ / 32, BH_), tb, 0, stream>>>(Vb, Vtb);

    colsum_k<<<dim3(S_ / 64, BH_), 256, 0, stream>>>(Qb, Kb, Lc);
    flash5_k<<<dim3(S_ / 64, BH_), 256, 0, stream>>>(Qb, Kb, Vtb, Lc, Zb);

    gemm_out_k<<<dim3(E_ / 128, BS_ / 128), 256, 0, stream>>>(Zb, Wzt, bZ, out);
}

// Round 6
// 772.139 us; speedup vs baseline: 1.7532x; 1.7532x over previous
//
#include <hip/hip_runtime.h>

typedef __attribute__((ext_vector_type(8))) short short8;
typedef __attribute__((ext_vector_type(4))) float f32x4;

constexpr int B_ = 4, S_ = 2048, E_ = 1024, H_ = 8, D_ = 256;
constexpr int HD_ = H_ * D_;   // 2048
constexpr int BS_ = B_ * S_;   // 8192
constexpr int BH_ = B_ * H_;   // 32
constexpr float INV_SQRT_E = 0.03125f;  // 1/sqrt(1024)

__device__ __forceinline__ unsigned short f2bf(float f) {
    union { float f; unsigned u; } x; x.f = f;
    unsigned r = (x.u + 0x7fffu + ((x.u >> 16) & 1u)) >> 16;
    return (unsigned short)r;
}

__device__ __forceinline__ void gl_lds16(const void* g, void* lds) {
    __builtin_amdgcn_global_load_lds((const __attribute__((address_space(1))) void*)g,
                                     (__attribute__((address_space(3))) void*)lds, 16, 0, 0);
}

// ---------------- cast A fp32 -> bf16 (vectorized) ----------------
__global__ __launch_bounds__(256) void cast_k(const float* __restrict__ src,
                                              unsigned short* __restrict__ dst, int n4) {
    int i = blockIdx.x * 256 + threadIdx.x;
    if (i >= n4) return;
    float4 v = reinterpret_cast<const float4*>(src)[i];
    ushort4 o;
    o.x = f2bf(v.x); o.y = f2bf(v.y); o.z = f2bf(v.z); o.w = f2bf(v.w);
    reinterpret_cast<ushort4*>(dst)[i] = o;
}

// ------------- batched transpose+cast: (bt,R,C) f32 -> (bt,C,R) bf16 -------------
__global__ __launch_bounds__(256) void tcast_k(const float* __restrict__ src,
                                               unsigned short* __restrict__ dst, int R, int C) {
    __shared__ float tile[32][33];
    int b = blockIdx.z;
    const float* s = src + (size_t)b * R * C;
    unsigned short* d = dst + (size_t)b * R * C;
    int c0 = blockIdx.x * 32, r0 = blockIdx.y * 32;
    int tx = threadIdx.x, ty = threadIdx.y;
#pragma unroll
    for (int i = 0; i < 4; ++i)
        tile[ty + i * 8][tx] = s[(size_t)(r0 + ty + i * 8) * C + c0 + tx];
    __syncthreads();
#pragma unroll
    for (int i = 0; i < 4; ++i)
        d[(size_t)(c0 + ty + i * 8) * R + r0 + tx] = f2bf(tile[tx][ty + i * 8]);
}

// ------------- bf16 transpose: (BH,S,D) -> (BH,D,S) -------------
__global__ __launch_bounds__(256) void tbf_k(const unsigned short* __restrict__ src,
                                             unsigned short* __restrict__ dst) {
    __shared__ unsigned short tile[32][33];
    int bh = blockIdx.z;
    int d0 = blockIdx.x * 32, s0 = blockIdx.y * 32;
    int tx = threadIdx.x, ty = threadIdx.y;
#pragma unroll
    for (int i = 0; i < 4; ++i)
        tile[ty + i * 8][tx] = src[((size_t)bh * S_ + s0 + ty + i * 8) * D_ + d0 + tx];
    __syncthreads();
#pragma unroll
    for (int i = 0; i < 4; ++i)
        dst[((size_t)bh * D_ + d0 + ty + i * 8) * S_ + s0 + tx] = tile[tx][ty + i * 8];
}

// ------------- QKV GEMM: A(BS,E) x Wt(n)[k] -> relu(+bias) -> (B,H,S,D) bf16 -------------
__global__ __launch_bounds__(256) void gemm_qkv_k(const unsigned short* __restrict__ A,
                                                  const unsigned short* __restrict__ Bt,
                                                  const float* __restrict__ bias,
                                                  unsigned short* __restrict__ out) {
    __shared__ __align__(16) unsigned short As[128 * 32];
    __shared__ __align__(16) unsigned short Bs[128 * 32];
    const int tid = threadIdx.x;
    const int wave = tid >> 6, lane = tid & 63;
    const int quad = lane >> 4, l15 = lane & 15;
    const int wm = wave >> 1, wn = wave & 1;
    const int m0 = blockIdx.y * 128, n0 = blockIdx.x * 128;
    const int c1 = tid, c2 = tid + 256;
    const int r1 = c1 >> 2, kc1 = (c1 & 3) * 8;
    const int r2 = c2 >> 2, kc2 = (c2 & 3) * 8;
    char* aB1 = (char*)As + wave * 1024; char* aB2 = aB1 + 4096;
    char* bB1 = (char*)Bs + wave * 1024; char* bB2 = bB1 + 4096;
    const unsigned short* a1 = A + (size_t)(m0 + r1) * E_ + kc1;
    const unsigned short* a2 = A + (size_t)(m0 + r2) * E_ + kc2;
    const unsigned short* b1 = Bt + (size_t)(n0 + r1) * E_ + kc1;
    const unsigned short* b2 = Bt + (size_t)(n0 + r2) * E_ + kc2;
    f32x4 acc[4][4] = {};
    for (int k0 = 0; k0 < E_; k0 += 32) {
        __syncthreads();
        gl_lds16(a1 + k0, aB1);
        gl_lds16(a2 + k0, aB2);
        gl_lds16(b1 + k0, bB1);
        gl_lds16(b2 + k0, bB2);
        __syncthreads();
        short8 af[4], bf[4];
        const short* Ass = (const short*)As;
        const short* Bss = (const short*)Bs;
#pragma unroll
        for (int f = 0; f < 4; ++f) {
            af[f] = *(const short8*)&Ass[(wm * 64 + f * 16 + l15) * 32 + quad * 8];
            bf[f] = *(const short8*)&Bss[(wn * 64 + f * 16 + l15) * 32 + quad * 8];
        }
#pragma unroll
        for (int fm = 0; fm < 4; ++fm)
#pragma unroll
            for (int fn = 0; fn < 4; ++fn)
                acc[fm][fn] = __builtin_amdgcn_mfma_f32_16x16x32_bf16(af[fm], bf[fn], acc[fm][fn], 0, 0, 0);
    }
#pragma unroll
    for (int fm = 0; fm < 4; ++fm) {
        int mbase = m0 + wm * 64 + fm * 16 + quad * 4;
#pragma unroll
        for (int fn = 0; fn < 4; ++fn) {
            int n = n0 + wn * 64 + fn * 16 + l15;
            int h = n >> 8, d = n & 255;
            float bv = bias[n];
#pragma unroll
            for (int r = 0; r < 4; ++r) {
                int m = mbase + r;
                int b = m >> 11, s = m & 2047;
                float v = fmaxf(acc[fm][fn][r] + bv, 0.0f);
                out[((size_t)(b * H_ + h) * S_ + s) * D_ + d] = f2bf(v);
            }
        }
    }
}

// ------------- output GEMM: Zall(BS,HD) x Wzt(n)[k] + bZ -> fp32 (BS,E) -------------
__global__ __launch_bounds__(256) void gemm_out_k(const unsigned short* __restrict__ A,
                                                  const unsigned short* __restrict__ Bt,
                                                  const float* __restrict__ bias,
                                                  float* __restrict__ out) {
    __shared__ __align__(16) unsigned short As[128 * 32];
    __shared__ __align__(16) unsigned short Bs[128 * 32];
    const int tid = threadIdx.x;
    const int wave = tid >> 6, lane = tid & 63;
    const int quad = lane >> 4, l15 = lane & 15;
    const int wm = wave >> 1, wn = wave & 1;
    const int m0 = blockIdx.y * 128, n0 = blockIdx.x * 128;
    const int c1 = tid, c2 = tid + 256;
    const int r1 = c1 >> 2, kc1 = (c1 & 3) * 8;
    const int r2 = c2 >> 2, kc2 = (c2 & 3) * 8;
    char* aB1 = (char*)As + wave * 1024; char* aB2 = aB1 + 4096;
    char* bB1 = (char*)Bs + wave * 1024; char* bB2 = bB1 + 4096;
    const unsigned short* a1 = A + (size_t)(m0 + r1) * HD_ + kc1;
    const unsigned short* a2 = A + (size_t)(m0 + r2) * HD_ + kc2;
    const unsigned short* b1 = Bt + (size_t)(n0 + r1) * HD_ + kc1;
    const unsigned short* b2 = Bt + (size_t)(n0 + r2) * HD_ + kc2;
    f32x4 acc[4][4] = {};
    for (int k0 = 0; k0 < HD_; k0 += 32) {
        __syncthreads();
        gl_lds16(a1 + k0, aB1);
        gl_lds16(a2 + k0, aB2);
        gl_lds16(b1 + k0, bB1);
        gl_lds16(b2 + k0, bB2);
        __syncthreads();
        short8 af[4], bf[4];
        const short* Ass = (const short*)As;
        const short* Bss = (const short*)Bs;
#pragma unroll
        for (int f = 0; f < 4; ++f) {
            af[f] = *(const short8*)&Ass[(wm * 64 + f * 16 + l15) * 32 + quad * 8];
            bf[f] = *(const short8*)&Bss[(wn * 64 + f * 16 + l15) * 32 + quad * 8];
        }
#pragma unroll
        for (int fm = 0; fm < 4; ++fm)
#pragma unroll
            for (int fn = 0; fn < 4; ++fn)
                acc[fm][fn] = __builtin_amdgcn_mfma_f32_16x16x32_bf16(af[fm], bf[fn], acc[fm][fn], 0, 0, 0);
    }
#pragma unroll
    for (int fm = 0; fm < 4; ++fm) {
        int mbase = m0 + wm * 64 + fm * 16 + quad * 4;
#pragma unroll
        for (int fn = 0; fn < 4; ++fn) {
            int n = n0 + wn * 64 + fn * 16 + l15;
            float bv = bias[n];
#pragma unroll
            for (int r = 0; r < 4; ++r)
                out[(size_t)(mbase + r) * E_ + n] = acc[fm][fn][r] + bv;
        }
    }
}

// ======== colsum_k: invL[t] = 1 / sum_s exp(sc[s][t]) (no max: scores bounded).
// Block owns 64 t-rows. K-tile staged in LDS ONCE; Q B-frags direct from global;
// ZERO barriers in the s-loop. ========
__global__ __launch_bounds__(256) void colsum_k(const unsigned short* __restrict__ Q,
                                                const unsigned short* __restrict__ K,
                                                float* __restrict__ invLcol) {
    __shared__ __align__(16) unsigned short Ks[8 * 64 * 32];  // [kc][row][32] = 32 KB
    __shared__ float part[4][64];
    const int tid = threadIdx.x;
    const int wave = tid >> 6, lane = tid & 63;
    const int quad = lane >> 4, l15 = lane & 15;
    const int bh = blockIdx.y;
    const int t0 = blockIdx.x * 64;
    const unsigned short* Qh = Q + (size_t)bh * S_ * D_;
    const unsigned short* Kh = K + (size_t)bh * S_ * D_;
    const int sr = tid >> 2, scol = (tid & 3) * 8;
#pragma unroll
    for (int kc = 0; kc < 8; ++kc)
        gl_lds16(Kh + (size_t)(t0 + sr) * D_ + kc * 32 + scol,
                 (char*)Ks + kc * 4096 + wave * 1024);
    __syncthreads();
    float rl[4][4] = {};
    for (int s0 = 0; s0 < S_; s0 += 128) {
        f32x4 acc[4][2] = {};
#pragma unroll
        for (int kc = 0; kc < 8; ++kc) {
            short8 af[4];
#pragma unroll
            for (int fm = 0; fm < 4; ++fm)
                af[fm] = *(const short8*)&Ks[kc * 2048 + (fm * 16 + l15) * 32 + quad * 8];
            short8 qb0 = *(const short8*)&Qh[(size_t)(s0 + wave * 32 + l15) * D_ + kc * 32 + quad * 8];
            short8 qb1 = *(const short8*)&Qh[(size_t)(s0 + wave * 32 + 16 + l15) * D_ + kc * 32 + quad * 8];
#pragma unroll
            for (int fm = 0; fm < 4; ++fm) {
                acc[fm][0] = __builtin_amdgcn_mfma_f32_16x16x32_bf16(af[fm], qb0, acc[fm][0], 0, 0, 0);
                acc[fm][1] = __builtin_amdgcn_mfma_f32_16x16x32_bf16(af[fm], qb1, acc[fm][1], 0, 0, 0);
            }
        }
#pragma unroll
        for (int fm = 0; fm < 4; ++fm)
#pragma unroll
            for (int r = 0; r < 4; ++r)
                rl[fm][r] += __expf(acc[fm][0][r] * INV_SQRT_E) +
                             __expf(acc[fm][1][r] * INV_SQRT_E);
    }
#pragma unroll
    for (int fm = 0; fm < 4; ++fm)
#pragma unroll
        for (int r = 0; r < 4; ++r) {
            float v = rl[fm][r];
            v += __shfl_xor(v, 1); v += __shfl_xor(v, 2);
            v += __shfl_xor(v, 4); v += __shfl_xor(v, 8);
            if (l15 == 0) part[wave][fm * 16 + quad * 4 + r] = v;
        }
    __syncthreads();
    if (tid < 64) {
        float s = part[0][tid] + part[1][tid] + part[2][tid] + part[3][tid];
        invLcol[(size_t)bh * S_ + t0 + tid] = 1.0f / s;
    }
}

// ======== flash6_k: flash4 structure (Qs staged in LDS once — proven L2-friendly)
// with t-tile 64 so LDS = Qs 32K + Ps 10K + rsum = 43.3 KB -> 3 blocks/CU.
// QK: waves split t (16 cols each), K B-frags from global; PV: waves split d,
// V B-frags from global, P A-frags from shared Ps. 2 barriers per 64-t tile. ========
__global__ __launch_bounds__(256, 3) void flash6_k(const unsigned short* __restrict__ Q,
                                                   const unsigned short* __restrict__ K,
                                                   const unsigned short* __restrict__ Vt,
                                                   const float* __restrict__ invLcol,
                                                   unsigned short* __restrict__ Zall) {
    __shared__ __align__(16) unsigned short Qs[8 * 64 * 32];   // [kc][row][32] = 32 KB
    __shared__ __align__(16) unsigned short Ps[2 * 64 * 40];   // [kk][row][40] = 10 KB
    __shared__ float rsum[64];
    const int tid = threadIdx.x;
    const int wave = tid >> 6, lane = tid & 63;
    const int quad = lane >> 4, l15 = lane & 15;
    const int bh = blockIdx.y;
    const int bb = bh >> 3, hh = bh & 7;
    const int s0 = blockIdx.x * 64;
    const unsigned short* Qh = Q + (size_t)bh * S_ * D_;
    const unsigned short* Kh = K + (size_t)bh * S_ * D_;
    const unsigned short* Vh = Vt + (size_t)bh * D_ * S_;
    const float* Lc = invLcol + (size_t)bh * S_;
    const int sr = tid >> 2, scol = (tid & 3) * 8;
#pragma unroll
    for (int kc = 0; kc < 8; ++kc)
        gl_lds16(Qh + (size_t)(s0 + sr) * D_ + kc * 32 + scol,
                 (char*)Qs + kc * 4096 + wave * 1024);
    if (tid < 64) rsum[tid] = 0.f;
    f32x4 zacc[4][4] = {};
    float rsacc[4][4] = {};
    __syncthreads();
    for (int t0 = 0; t0 < S_; t0 += 64) {
        // QK: this wave owns t-cols [t0+wave*16, t0+wave*16+16)
        f32x4 acc[4] = {};
        float Li = Lc[t0 + wave * 16 + l15];
#pragma unroll
        for (int kc = 0; kc < 8; ++kc) {
            short8 kb = *(const short8*)&Kh[(size_t)(t0 + wave * 16 + l15) * D_ + kc * 32 + quad * 8];
#pragma unroll
            for (int fm = 0; fm < 4; ++fm) {
                short8 af = *(const short8*)&Qs[kc * 2048 + (fm * 16 + l15) * 32 + quad * 8];
                acc[fm] = __builtin_amdgcn_mfma_f32_16x16x32_bf16(af, kb, acc[fm], 0, 0, 0);
            }
        }
        // exp(exp(sc)*invL) -> Ps [kk = wave>>1][row][40], col (wave&1)*16 + l15
#pragma unroll
        for (int fm = 0; fm < 4; ++fm)
#pragma unroll
            for (int r = 0; r < 4; ++r) {
                float e = __expf(__expf(acc[fm][r] * INV_SQRT_E) * Li);
                rsacc[fm][r] += e;
                int row = fm * 16 + quad * 4 + r;
                Ps[(wave >> 1) * 2560 + row * 40 + (wave & 1) * 16 + l15] = f2bf(e);
            }
        __syncthreads();
        // PV: waves split d (64 cols each); A-frags from Ps, B-frags (Vt) from global
#pragma unroll
        for (int kk = 0; kk < 2; ++kk) {
            short8 pa[4], vb[4];
#pragma unroll
            for (int fm = 0; fm < 4; ++fm)
                pa[fm] = *(const short8*)&Ps[kk * 2560 + (fm * 16 + l15) * 40 + quad * 8];
#pragma unroll
            for (int fn = 0; fn < 4; ++fn)
                vb[fn] = *(const short8*)&Vh[(size_t)(wave * 64 + fn * 16 + l15) * S_ + t0 + kk * 32 + quad * 8];
#pragma unroll
            for (int fm = 0; fm < 4; ++fm)
#pragma unroll
                for (int fn = 0; fn < 4; ++fn)
                    zacc[fm][fn] = __builtin_amdgcn_mfma_f32_16x16x32_bf16(pa[fm], vb[fn], zacc[fm][fn], 0, 0, 0);
        }
        __syncthreads();
    }
    // rowsum: each wave holds partials (its 16 t-cols per tile) for ALL 64 rows
#pragma unroll
    for (int fm = 0; fm < 4; ++fm)
#pragma unroll
        for (int r = 0; r < 4; ++r) {
            float v = rsacc[fm][r];
            v += __shfl_xor(v, 1); v += __shfl_xor(v, 2);
            v += __shfl_xor(v, 4); v += __shfl_xor(v, 8);
            if (l15 == 0) atomicAdd(&rsum[fm * 16 + quad * 4 + r], v);
        }
    __syncthreads();
#pragma unroll
    for (int fm = 0; fm < 4; ++fm)
#pragma unroll
        for (int r = 0; r < 4; ++r) {
            int row = fm * 16 + quad * 4 + r;
            float inv = 1.0f / rsum[row];
#pragma unroll
            for (int fn = 0; fn < 4; ++fn)
                Zall[(size_t)(bb * S_ + s0 + row) * HD_ + hh * D_ + wave * 64 + fn * 16 + l15] =
                    f2bf(zacc[fm][fn][r] * inv);
        }
}

extern "C" void kernel_launch(void* const* d_in, const int* in_sizes, int n_in,
                              void* d_out, int out_size, void* d_ws, size_t ws_size,
                              hipStream_t stream) {
    const float* Ain = (const float*)d_in[0];
    const float* WQ = (const float*)d_in[1];
    const float* bQ = (const float*)d_in[2];
    const float* WK = (const float*)d_in[3];
    const float* bK = (const float*)d_in[4];
    const float* WV = (const float*)d_in[5];
    const float* bV = (const float*)d_in[6];
    const float* WZ = (const float*)d_in[7];
    const float* bZ = (const float*)d_in[8];
    float* out = (float*)d_out;

    char* ws = (char*)d_ws;
    size_t off = 0;
    auto alloc = [&](size_t bytes) {
        char* p = ws + off;
        off += (bytes + 255) & ~(size_t)255;
        return p;
    };
    unsigned short* Abf = (unsigned short*)alloc((size_t)BS_ * E_ * 2);
    unsigned short* Wqt = (unsigned short*)alloc((size_t)H_ * D_ * E_ * 2);
    unsigned short* Wkt = (unsigned short*)alloc((size_t)H_ * D_ * E_ * 2);
    unsigned short* Wvt = (unsigned short*)alloc((size_t)H_ * D_ * E_ * 2);
    unsigned short* Wzt = (unsigned short*)alloc((size_t)E_ * HD_ * 2);
    unsigned short* Qb = (unsigned short*)alloc((size_t)BH_ * S_ * D_ * 2);
    unsigned short* Kb = (unsigned short*)alloc((size_t)BH_ * S_ * D_ * 2);
    unsigned short* Vb = (unsigned short*)alloc((size_t)BH_ * S_ * D_ * 2);
    unsigned short* Vtb = (unsigned short*)alloc((size_t)BH_ * S_ * D_ * 2);
    unsigned short* Zb = (unsigned short*)alloc((size_t)BS_ * HD_ * 2);
    float* Lc = (float*)alloc((size_t)BH_ * S_ * 4);

    dim3 tb(32, 8);
    cast_k<<<(BS_ * E_ / 4 + 255) / 256, 256, 0, stream>>>(Ain, Abf, BS_ * E_ / 4);
    tcast_k<<<dim3(D_ / 32, E_ / 32, H_), tb, 0, stream>>>(WQ, Wqt, E_, D_);
    tcast_k<<<dim3(D_ / 32, E_ / 32, H_), tb, 0, stream>>>(WK, Wkt, E_, D_);
    tcast_k<<<dim3(D_ / 32, E_ / 32, H_), tb, 0, stream>>>(WV, Wvt, E_, D_);
    tcast_k<<<dim3(E_ / 32, HD_ / 32, 1), tb, 0, stream>>>(WZ, Wzt, HD_, E_);

    gemm_qkv_k<<<dim3(HD_ / 128, BS_ / 128), 256, 0, stream>>>(Abf, Wqt, bQ, Qb);
    gemm_qkv_k<<<dim3(HD_ / 128, BS_ / 128), 256, 0, stream>>>(Abf, Wkt, bK, Kb);
    gemm_qkv_k<<<dim3(HD_ / 128, BS_ / 128), 256, 0, stream>>>(Abf, Wvt, bV, Vb);

    tbf_k<<<dim3(D_ / 32, S_ / 32, BH_), tb, 0, stream>>>(Vb, Vtb);

    colsum_k<<<dim3(S_ / 64, BH_), 256, 0, stream>>>(Qb, Kb, Lc);
    flash6_k<<<dim3(S_ / 64, BH_), 256, 0, stream>>>(Qb, Kb, Vtb, Lc, Zb);

    gemm_out_k<<<dim3(E_ / 128, BS_ / 128), 256, 0, stream>>>(Zb, Wzt, bZ, out);
}